// Round 7
// baseline (343.539 us; speedup 1.0000x reference)
//
#include <hip/hip_runtime.h>

#define S_LEN  2048
#define BATCH  1024
#define NL     6
#define CH     16      // timesteps per chunk (x-prefetch granularity)

typedef float f32x2 __attribute__((ext_vector_type(2)));

__device__ __forceinline__ float fexp2(float x) { return __builtin_amdgcn_exp2f(x); }
__device__ __forceinline__ float frcp(float x)  { return __builtin_amdgcn_rcpf(x); }

// quad_perm DPP: 0xB1 = lane^1 (pair partner), 0x4E = lane^2 (unit^1)
template <int CTRL>
__device__ __forceinline__ float dppf(float v) {
    return __int_as_float(__builtin_amdgcn_update_dpp(
        0, __float_as_int(v), CTRL, 0xF, 0xF, true));
}
__device__ __forceinline__ float bpermf(int addr, float v) {
    return __int_as_float(__builtin_amdgcn_ds_bpermute(addr, __float_as_int(v)));
}
// lane^4 exchange (unit^2) via ds_swizzle BitMode: xor=4, and=0x1F -> 0x101F
__device__ __forceinline__ float swz4(float v) {
    return __int_as_float(__builtin_amdgcn_ds_swizzle(__float_as_int(v), 0x101F));
}
// packed fp32 fma: d.lo = a.lo*b.lo + c.lo ; d.hi = a.hi*b.hi + c.hi
__device__ __forceinline__ f32x2 pkfma(f32x2 a, f32x2 b, f32x2 c) {
    f32x2 d;
    asm("v_pk_fma_f32 %0, %1, %2, %3" : "=v"(d) : "v"(a), "v"(b), "v"(c));
    return d;
}

// ONE wave = ONE batch element; 1024 waves fill all 1024 SIMDs.
// lane = L*8 + u*2 + p: L 0..5 layers, L=6 head, L=7 feeders; u = unit,
// p = gate-pair (p=0 -> {i,f}, p=1 -> {g,o}). 8 pkfma/step as in R6.
//
// SKEW-2 pipeline: layer L at step n computes t = n - 2L. The layer-handoff
// bpermute therefore has TWO steps of slack and leaves the critical chain.
// Banked operands: hupC (this step) / hupN (next, in flight); P2xC/P2yC
// staged one step ahead (P2y = swz4 of the landed hup -> only 1 bperm/step).
// Both parities compute valid cn/hn via X/Y partner exchange + fsel/ssel,
// so no post-hn h-merge is needed. Cell state kept KGc-scaled (c' = KGc*c)
// so exp2(cn') needs no multiply. Head rides in the C1.y chain of L=6 lanes.
__global__ __launch_bounds__(64, 1) void lstm_wavepipe(
    const float* __restrict__ x, const float* __restrict__ w_ih,
    const float* __restrict__ w_hh, const float* __restrict__ b_ih,
    const float* __restrict__ b_hh, const float* __restrict__ reg_w,
    const float* __restrict__ reg_b, float* __restrict__ out) {
    const int lane = threadIdx.x;
    const int L    = lane >> 3;
    const int q    = lane & 7;
    const int u    = q >> 1;
    const bool pOdd = (lane & 1);
    const int b    = blockIdx.x;
    const bool isFeeder = (L == 7);
    const bool isOut    = (lane == 48);      // head lane u=0,p=0

    const float KGc = -2.885390082f;         // -2*log2(e)  (tanh scale)
    const float KIc = -1.442695041f;         // -log2(e)    (sigmoid scale)

    // ---- weight preload (R6 layout): C1 {loGate-h, hiGate-hup},
    //      C2 {hiGate-h, loGate-hup}; gateLo = C1.x+C2.y, gateHi = C1.y+C2.x
    f32x2 A1[4], A2[4], PB;
    if (L < NL) {
        const int gLo = pOdd ? 2 : 0;        // i or g
        const int gHi = pOdd ? 3 : 1;        // f or o
        const float klo = pOdd ? KGc : KIc;
        const float khi = KIc;
        const int rowLo = L * 16 + gLo * 4 + u;
        const int rowHi = L * 16 + gHi * 4 + u;
#pragma unroll
        for (int m = 0; m < 4; ++m) {
            const int cm = u ^ m;
            f32x2 a1, a2;
            a1.x = w_hh[rowLo * 4 + cm] * klo;
            a1.y = w_ih[rowHi * 4 + cm] * khi;
            a2.x = w_hh[rowHi * 4 + cm] * khi;
            a2.y = w_ih[rowLo * 4 + cm] * klo;
            A1[m] = a1; A2[m] = a2;
        }
        PB.x = (b_ih[rowLo] + b_hh[rowLo]) * klo;
        PB.y = (b_ih[rowHi] + b_hh[rowHi]) * khi;
    } else if (L == 6) {                     // head: dot(reg_w, hup) in C1.y
#pragma unroll
        for (int m = 0; m < 4; ++m) {
            f32x2 a1; a1.x = 0.0f; a1.y = reg_w[u ^ m];
            A1[m] = a1;
            f32x2 a2; a2.x = 0.0f; a2.y = 0.0f;
            A2[m] = a2;
        }
        PB.x = 0.0f; PB.y = reg_b[0];
    } else {                                 // feeders: all zero
#pragma unroll
        for (int m = 0; m < 4; ++m) {
            f32x2 z; z.x = 0.0f; z.y = 0.0f;
            A1[m] = z; A2[m] = z;
        }
        PB.x = 0.0f; PB.y = 0.0f;
    }
    // sA = fma(aLo, rA, bLo): p0 -> KGc*sigmoid(i) (pre-scaled for cn'),
    //                         p1 -> tanh(g) = 2*sig-1
    const float aLo = pOdd ? 2.0f : KGc;
    const float bLo = pOdd ? -1.0f : 0.0f;
    f32x2 Z2; Z2.x = 0.0f; Z2.y = 0.0f;

    const int addrA = (((lane >= 8) ? (lane - 8) : (lane + 56)) << 2);

    float h = 0.0f, cp = 0.0f;               // cp = KGc-scaled cell state
    float bufP[CH], bufQ[CH], su[CH];
    const uint32_t xcol = (uint32_t)(b * 4 + u);
    uint32_t wi = xcol;
#pragma unroll
    for (int uu = 0; uu < CH; ++uu) { bufP[uu] = x[wi]; wi += 4096; }  // t=0..15

    // prologue: hup for steps 0 and 1 (feeders publish x[0], x[1]; h=0 else)
    const float pub0 = isFeeder ? bufP[0] : 0.0f;
    const float pub1 = isFeeder ? bufP[1] : 0.0f;
    float hupC = bpermf(addrA, pub0);        // for step 0
    float hupN = bpermf(addrA, pub1);        // for step 1
    float P2xC = 0.0f;                       // swz4(h=0)
    float P2yC = swz4(hupC);                 // for step 0
    // P2x/P2y for step 1 are produced by step 0's body.

// one pipeline step; NXV_ = x value the feeders publish for step n+2
#define STEP(u_, NXV_, MASKF_) do {                                            \
    f32x2 P0, P1, P2, P3;                                                      \
    P0.x = h;    P0.y = hupC;                                                  \
    P2.x = P2xC; P2.y = P2yC;                                                  \
    P1.x = dppf<0x4E>(P0.x); P1.y = dppf<0x4E>(P0.y);                          \
    P3.x = dppf<0x4E>(P2.x); P3.y = dppf<0x4E>(P2.y);                          \
    f32x2 C1 = pkfma(A1[0], P0, PB);                                           \
    f32x2 C2 = pkfma(A2[0], P0, Z2);                                           \
    C1 = pkfma(A1[1], P1, C1); C2 = pkfma(A2[1], P1, C2);                      \
    C1 = pkfma(A1[2], P2, C1); C2 = pkfma(A2[2], P2, C2);                      \
    C1 = pkfma(A1[3], P3, C1); C2 = pkfma(A2[3], P3, C2);                      \
    const float P2yN_ = swz4(hupN);          /* stage P2y for step n+1 */      \
    const float gLo = C1.x + C2.y;                                             \
    const float gHi = C1.y + C2.x;                                             \
    const float rA = frcp(1.0f + fexp2(gLo));                                  \
    const float rB = frcp(1.0f + fexp2(gHi));                                  \
    const float sA = fmaf(aLo, rA, bLo);     /* p0: KGc*si ; p1: tanh(g) */    \
    const float X  = dppf<0xB1>(sA);                                           \
    const float Y  = dppf<0xB1>(rB);                                           \
    const float fsel = pOdd ? Y : rB;        /* sigmoid(f) on both lanes */    \
    const float ssel = pOdd ? rB : Y;        /* sigmoid(o) on both lanes */    \
    const float prod = sA * X;               /* KGc*si*tg on both lanes */     \
    const float cnp  = fmaf(fsel, cp, prod); /* KGc-scaled cell */             \
    const float th   = fmaf(2.0f, frcp(1.0f + fexp2(cnp)), -1.0f);             \
    const float hn   = ssel * th;                                              \
    float hpost, cpost;                                                        \
    if (MASKF_) {                                                              \
        const bool act = (u_ >= 2 * L);      /* skew-2 pipeline-fill gate */   \
        cpost = act ? cnp : cp;                                                \
        hpost = act ? hn : h;                                                  \
    } else { cpost = cnp; hpost = hn; }                                        \
    cp = cpost;                                                                \
    su[u_] = gHi;                            /* head value on L=6 lanes */     \
    const float P2xN_ = swz4(hpost);         /* own-layer u^2, step n+1 */     \
    const float hpub  = isFeeder ? (NXV_) : hpost;                             \
    const float hupN2 = bpermf(addrA, hpub); /* layer handoff, step n+2 */     \
    h = hpost;                                                                 \
    hupC = hupN; hupN = hupN2;                                                 \
    P2xC = P2xN_; P2yC = P2yN_;                                                \
} while (0)

// PREFM_: 0=no prefetch, 1=stream next 16 t's, 2=clamped (replicate t=2047)
#define RUN_CHUNK(cc_, cur_, nxt_, MASKF_, PREFM_, GUARDF_, NSTEPS_) do {      \
    if ((PREFM_) == 1) {                                                       \
        _Pragma("unroll")                                                      \
        for (int uu = 0; uu < CH; ++uu) { nxt_[uu] = x[wi]; wi += 4096; }      \
    } else if ((PREFM_) == 2) {                                                \
        const float xl = x[2047u * 4096u + xcol];                              \
        _Pragma("unroll")                                                      \
        for (int uu = 0; uu < CH; ++uu) nxt_[uu] = xl;                         \
    }                                                                          \
    _Pragma("unroll")                                                          \
    for (int uu = 0; uu < (NSTEPS_); ++uu) {                                   \
        if (uu < CH - 2)       STEP(uu, cur_[uu + 2], MASKF_);                 \
        else if (uu == CH - 2) STEP(uu, nxt_[0],      MASKF_);                 \
        else                   STEP(uu, nxt_[1],      MASKF_);                 \
    }                                                                          \
    if (isOut) {                                                               \
        const int base = (cc_) * CH - 12;    /* head lags input by 12 steps */ \
        _Pragma("unroll")                                                      \
        for (int uu = 0; uu < (NSTEPS_); ++uu) {                               \
            const int t = base + uu;                                           \
            if (!(GUARDF_) || ((t >= 0) && (t < S_LEN)))                       \
                out[(size_t)t * BATCH + b] = su[uu];                           \
        }                                                                      \
    }                                                                          \
} while (0)

    // chunk 0: masked (pipeline fill), prefetch t=16..31 into bufQ
    RUN_CHUNK(0, bufP, bufQ, 1, 1, 1, CH);
    // bulk: chunks 1..126, maskless, guardless, ping-pong buffers
#pragma unroll 1
    for (int cc = 1; cc < 127; cc += 2) {
        RUN_CHUNK(cc,     bufQ, bufP, 0, 1, 0, CH);
        RUN_CHUNK(cc + 1, bufP, bufQ, 0, 1, 0, CH);
    }
    // chunk 127: last real x tile; clamped prefetch (t=2047 replicated)
    RUN_CHUNK(127, bufQ, bufP, 0, 2, 0, CH);
    // chunk 128: 12 drain steps emit head values for t=2036..2047
    RUN_CHUNK(128, bufP, bufQ, 0, 0, 0, 12);
#undef RUN_CHUNK
#undef STEP
}

extern "C" void kernel_launch(void* const* d_in, const int* in_sizes, int n_in,
                              void* d_out, int out_size, void* d_ws, size_t ws_size,
                              hipStream_t stream) {
    const float* x     = (const float*)d_in[0];
    const float* w_ih  = (const float*)d_in[1];
    const float* w_hh  = (const float*)d_in[2];
    const float* b_ih  = (const float*)d_in[3];
    const float* b_hh  = (const float*)d_in[4];
    const float* reg_w = (const float*)d_in[5];
    const float* reg_b = (const float*)d_in[6];
    float* out = (float*)d_out;

    // 1024 single-wave blocks, one batch element each: 1 wave per SIMD.
    dim3 grid(BATCH);
    dim3 block(64);
    hipLaunchKernelGGL(lstm_wavepipe, grid, block, 0, stream, x, w_ih, w_hh,
                       b_ih, b_hh, reg_w, reg_b, out);
}

// Round 8
// 324.729 us; speedup vs baseline: 1.0579x; 1.0579x over previous
//
#include <hip/hip_runtime.h>

#define S_LEN  2048
#define BATCH  1024
#define NL     6
#define CH     16      // timesteps per chunk (x-prefetch granularity)

typedef float f32x2 __attribute__((ext_vector_type(2)));

__device__ __forceinline__ float fexp2(float x) { return __builtin_amdgcn_exp2f(x); }
__device__ __forceinline__ float frcp(float x)  { return __builtin_amdgcn_rcpf(x); }

// quad_perm DPP: 0xB1 = lane^1 (pair partner), 0x4E = lane^2 (unit^1)
template <int CTRL>
__device__ __forceinline__ float dppf(float v) {
    return __int_as_float(__builtin_amdgcn_update_dpp(
        0, __float_as_int(v), CTRL, 0xF, 0xF, true));
}
__device__ __forceinline__ float bpermf(int addr, float v) {
    return __int_as_float(__builtin_amdgcn_ds_bpermute(addr, __float_as_int(v)));
}
// lane^4 exchange (unit^2) via ds_swizzle BitMode: xor=4, and=0x1F -> 0x101F
__device__ __forceinline__ float swz4(float v) {
    return __int_as_float(__builtin_amdgcn_ds_swizzle(__float_as_int(v), 0x101F));
}
// packed fp32 fma: d.lo = a.lo*b.lo + c.lo ; d.hi = a.hi*b.hi + c.hi
__device__ __forceinline__ f32x2 pkfma(f32x2 a, f32x2 b, f32x2 c) {
    f32x2 d;
    asm("v_pk_fma_f32 %0, %1, %2, %3" : "=v"(d) : "v"(a), "v"(b), "v"(c));
    return d;
}

// ONE wave = ONE batch element; 1024 waves fill all 1024 SIMDs.
// lane = L*8 + u*2 + p: L 0..5 layers, L=6 head, L=7 feeders; u = unit,
// p = gate-pair (p=0 -> {i,f}, p=1 -> {g,o}).
//
// SKEW-2 pipeline (layer L at step n computes t = n - 2L) as in R7, PLUS:
// the hup-half of each gate sum (E1/E2 = sum wih*hup + bias) is PRECOMPUTED
// one step ahead -- hup for step n+1 landed at step n -- so (a) the E-block
// is ~9 insts of chain-independent ILP placed inside the activation-latency
// window, and (b) the h-dependent pkfma chain is only 2 hops (F = E + h-part).
// Gate split: gLo = F1.x + F2.y, gHi = F1.y + F2.x.
// Both parities compute valid cn/hn (X/Y partner exchange); cell state kept
// KGc-scaled; head rides in the gHi chain of L=6 lanes (hup coefficients).
__global__ __launch_bounds__(64, 1) void lstm_wavepipe(
    const float* __restrict__ x, const float* __restrict__ w_ih,
    const float* __restrict__ w_hh, const float* __restrict__ b_ih,
    const float* __restrict__ b_hh, const float* __restrict__ reg_w,
    const float* __restrict__ reg_b, float* __restrict__ out) {
    const int lane = threadIdx.x;
    const int L    = lane >> 3;
    const int q    = lane & 7;
    const int u    = q >> 1;
    const bool pOdd = (lane & 1);
    const int b    = blockIdx.x;
    const bool isFeeder = (L == 7);
    const bool isOut    = (lane == 48);      // head lane u=0,p=0

    const float KGc = -2.885390082f;         // -2*log2(e)  (tanh scale)
    const float KIc = -1.442695041f;         // -log2(e)    (sigmoid scale)

    // ---- weight preload ----
    // F1.x: gateLo h-terms {u, u^2}; F1.y: gateHi h-terms {u^1, u^3}
    // F2.x: gateHi h-terms {u, u^2}; F2.y: gateLo h-terms {u^1, u^3}
    // E1/E2 same pattern with wih (hup terms); biases in PB (E1 seed).
    f32x2 A1h[2], A2h[2], B1h[2], B2h[2], PB;
    if (L < NL) {
        const int gLoI = pOdd ? 2 : 0;       // i or g
        const int gHiI = pOdd ? 3 : 1;       // f or o
        const float klo = pOdd ? KGc : KIc;
        const float khi = KIc;
        const int rowLo = L * 16 + gLoI * 4 + u;
        const int rowHi = L * 16 + gHiI * 4 + u;
#pragma unroll
        for (int k = 0; k < 2; ++k) {        // k=0: {u,u^1}; k=1: {u^2,u^3}
            const int c0 = u ^ (2 * k);      // u, u^2
            const int c1 = u ^ (2 * k + 1);  // u^1, u^3
            f32x2 a1, a2, b1, b2;
            a1.x = w_hh[rowLo * 4 + c0] * klo; a1.y = w_hh[rowHi * 4 + c1] * khi;
            a2.x = w_hh[rowHi * 4 + c0] * khi; a2.y = w_hh[rowLo * 4 + c1] * klo;
            b1.x = w_ih[rowLo * 4 + c0] * klo; b1.y = w_ih[rowHi * 4 + c1] * khi;
            b2.x = w_ih[rowHi * 4 + c0] * khi; b2.y = w_ih[rowLo * 4 + c1] * klo;
            A1h[k] = a1; A2h[k] = a2; B1h[k] = b1; B2h[k] = b2;
        }
        PB.x = (b_ih[rowLo] + b_hh[rowLo]) * klo;
        PB.y = (b_ih[rowHi] + b_hh[rowHi]) * khi;
    } else if (L == 6) {                     // head: dot(reg_w, hup) in gHi
#pragma unroll
        for (int k = 0; k < 2; ++k) {
            f32x2 z; z.x = 0.0f; z.y = 0.0f;
            A1h[k] = z; A2h[k] = z;
            f32x2 b1; b1.x = 0.0f; b1.y = reg_w[u ^ (2 * k + 1)];
            f32x2 b2; b2.x = reg_w[u ^ (2 * k)]; b2.y = 0.0f;
            B1h[k] = b1; B2h[k] = b2;
        }
        PB.x = 0.0f; PB.y = reg_b[0];
    } else {                                 // feeders: all zero
#pragma unroll
        for (int k = 0; k < 2; ++k) {
            f32x2 z; z.x = 0.0f; z.y = 0.0f;
            A1h[k] = z; A2h[k] = z; B1h[k] = z; B2h[k] = z;
        }
        PB.x = 0.0f; PB.y = 0.0f;
    }
    // sA = fma(aLo, rA, bLo): p0 -> KGc*sigmoid(i), p1 -> tanh(g)
    const float aLo = pOdd ? 2.0f : KGc;
    const float bLo = pOdd ? -1.0f : 0.0f;
    f32x2 Z2; Z2.x = 0.0f; Z2.y = 0.0f;

    const int addrA = (((lane >= 8) ? (lane - 8) : (lane + 56)) << 2);

    float cp = 0.0f;                         // KGc-scaled cell state
    f32x2 H;  H.x = 0.0f;  H.y = 0.0f;       // {h, h^1}
    f32x2 H2; H2.x = 0.0f; H2.y = 0.0f;      // {h^2, h^3} (x staged via swz4)
    float bufP[CH], bufQ[CH], su[CH];
    const uint32_t xcol = (uint32_t)(b * 4 + u);
    uint32_t wi = xcol;
#pragma unroll
    for (int uu = 0; uu < CH; ++uu) { bufP[uu] = x[wi]; wi += 4096; }  // t=0..15

    // prologue: hup for step 0 -> E1c/E2c; hup for step 1 -> hupN
    const float pub0 = isFeeder ? bufP[0] : 0.0f;
    const float pub1 = isFeeder ? bufP[1] : 0.0f;
    f32x2 E1c, E2c;
    {
        f32x2 U0, U20;
        U0.x = bpermf(addrA, pub0);
        U20.x = swz4(U0.x);
        U0.y  = dppf<0x4E>(U0.x);
        U20.y = dppf<0x4E>(U20.x);
        E1c = pkfma(B1h[1], U20, pkfma(B1h[0], U0, PB));
        E2c = pkfma(B2h[1], U20, pkfma(B2h[0], U0, Z2));
    }
    float hupN = bpermf(addrA, pub1);        // hup for step 1

// one pipeline step; NXV_ = x value the feeders publish (consumed at n+2)
#define STEP(u_, NXV_, MASKF_) do {                                            \
    /* own-h operand halves */                                                 \
    H.y  = dppf<0x4E>(H.x);                                                    \
    H2.y = dppf<0x4E>(H2.x);                                                   \
    /* gate sums: 2-hop h-chain on top of precomputed hup-part */              \
    f32x2 F1 = pkfma(A1h[1], H2, E1c);                                         \
    f32x2 F2 = pkfma(A2h[1], H2, E2c);                                         \
    F1 = pkfma(A1h[0], H, F1);                                                 \
    F2 = pkfma(A2h[0], H, F2);                                                 \
    const float gLo = F1.x + F2.y;                                             \
    const float gHi = F1.y + F2.x;                                             \
    /* E-precompute for step n+1 from landed hupN: pure ILP filler */          \
    f32x2 Un, U2n;                                                             \
    U2n.x = swz4(hupN);                                                        \
    Un.x  = hupN;                                                              \
    Un.y  = dppf<0x4E>(hupN);                                                  \
    f32x2 E1n = pkfma(B1h[0], Un, PB);                                         \
    f32x2 E2n = pkfma(B2h[0], Un, Z2);                                         \
    U2n.y = dppf<0x4E>(U2n.x);                                                 \
    E1n = pkfma(B1h[1], U2n, E1n);                                             \
    E2n = pkfma(B2h[1], U2n, E2n);                                             \
    /* activations */                                                          \
    const float rA = frcp(1.0f + fexp2(gLo));                                  \
    const float rB = frcp(1.0f + fexp2(gHi));                                  \
    const float sA = fmaf(aLo, rA, bLo);     /* p0: KGc*si ; p1: tanh(g) */    \
    const float X  = dppf<0xB1>(sA);                                           \
    const float Y  = dppf<0xB1>(rB);                                           \
    const float fsel = pOdd ? Y : rB;        /* sigmoid(f) on both lanes */    \
    const float ssel = pOdd ? rB : Y;        /* sigmoid(o) on both lanes */    \
    const float prod = sA * X;               /* KGc*si*tg on both lanes */     \
    const float cnp  = fmaf(fsel, cp, prod); /* KGc-scaled cell */             \
    const float th   = fmaf(2.0f, frcp(1.0f + fexp2(cnp)), -1.0f);             \
    const float hn   = ssel * th;                                              \
    float hpost, cpost;                                                        \
    if (MASKF_) {                                                              \
        const bool act = (u_ >= 2 * L);      /* skew-2 pipeline-fill gate */   \
        cpost = act ? cnp : cp;                                                \
        hpost = act ? hn : H.x;                                                \
    } else { cpost = cnp; hpost = hn; }                                        \
    cp = cpost;                                                                \
    su[u_] = gHi;                            /* head value on L=6 lanes */     \
    /* staging for next steps */                                               \
    H2.x = swz4(hpost);                      /* own u^2, step n+1 */           \
    const float hpub = isFeeder ? (NXV_) : hpost;                              \
    hupN = bpermf(addrA, hpub);              /* hup consumed at n+1's E */     \
    H.x = hpost;                                                               \
    E1c = E1n; E2c = E2n;                                                      \
} while (0)

// PREFM_: 0=no prefetch, 1=stream next 16 t's, 2=clamped (replicate t=2047)
#define RUN_CHUNK(cc_, cur_, nxt_, MASKF_, PREFM_, GUARDF_, NSTEPS_) do {      \
    if ((PREFM_) == 1) {                                                       \
        _Pragma("unroll")                                                      \
        for (int uu = 0; uu < CH; ++uu) { nxt_[uu] = x[wi]; wi += 4096; }      \
    } else if ((PREFM_) == 2) {                                                \
        const float xl = x[2047u * 4096u + xcol];                              \
        _Pragma("unroll")                                                      \
        for (int uu = 0; uu < CH; ++uu) nxt_[uu] = xl;                         \
    }                                                                          \
    _Pragma("unroll")                                                          \
    for (int uu = 0; uu < (NSTEPS_); ++uu) {                                   \
        if (uu < CH - 2)       STEP(uu, cur_[uu + 2], MASKF_);                 \
        else if (uu == CH - 2) STEP(uu, nxt_[0],      MASKF_);                 \
        else                   STEP(uu, nxt_[1],      MASKF_);                 \
    }                                                                          \
    if (isOut) {                                                               \
        const int base = (cc_) * CH - 12;    /* head lags input by 12 steps */ \
        _Pragma("unroll")                                                      \
        for (int uu = 0; uu < (NSTEPS_); ++uu) {                               \
            const int t = base + uu;                                           \
            if (!(GUARDF_) || ((t >= 0) && (t < S_LEN)))                       \
                out[(size_t)t * BATCH + b] = su[uu];                           \
        }                                                                      \
    }                                                                          \
} while (0)

    // chunk 0: masked (pipeline fill), prefetch t=16..31 into bufQ
    RUN_CHUNK(0, bufP, bufQ, 1, 1, 1, CH);
    // bulk: chunks 1..126, maskless, guardless, ping-pong buffers
#pragma unroll 1
    for (int cc = 1; cc < 127; cc += 2) {
        RUN_CHUNK(cc,     bufQ, bufP, 0, 1, 0, CH);
        RUN_CHUNK(cc + 1, bufP, bufQ, 0, 1, 0, CH);
    }
    // chunk 127: last real x tile; clamped prefetch (t=2047 replicated)
    RUN_CHUNK(127, bufQ, bufP, 0, 2, 0, CH);
    // chunk 128: 12 drain steps emit head values for t=2036..2047
    RUN_CHUNK(128, bufP, bufQ, 0, 0, 0, 12);
#undef RUN_CHUNK
#undef STEP
}

extern "C" void kernel_launch(void* const* d_in, const int* in_sizes, int n_in,
                              void* d_out, int out_size, void* d_ws, size_t ws_size,
                              hipStream_t stream) {
    const float* x     = (const float*)d_in[0];
    const float* w_ih  = (const float*)d_in[1];
    const float* w_hh  = (const float*)d_in[2];
    const float* b_ih  = (const float*)d_in[3];
    const float* b_hh  = (const float*)d_in[4];
    const float* reg_w = (const float*)d_in[5];
    const float* reg_b = (const float*)d_in[6];
    float* out = (float*)d_out;

    // 1024 single-wave blocks, one batch element each: 1 wave per SIMD.
    dim3 grid(BATCH);
    dim3 block(64);
    hipLaunchKernelGGL(lstm_wavepipe, grid, block, 0, stream, x, w_ih, w_hh,
                       b_ih, b_hh, reg_w, reg_b, out);
}